// Round 13
// baseline (884.549 us; speedup 1.0000x reference)
//
#include <hip/hip_runtime.h>

// 2-layer LSTM, B=2048, T=4096, IN=1, H=8, OUT=1, fp32.
//
// R20 = R15 (best, 855us) + TREE-FORM dots on the z-critical legs only.
// Serial 4-fma am1 gave h->z depth 7 (4 fma + permlane + cndmask + add);
// tree (q0=fma(w1,h1,w0*h0); q1=fma(w3,h3,w2*h2); am1=q0+q1) gives
// depth 3 -> s1-leg depth 6. an1 likewise treed (t0 init); z formed as
// (a1+p1)+s1 so the near leg is depth 3 pre-combine. am2/an2 stay
// serial (slack-covered; tree would add insts for no chain gain).
// +2 issued insts total, -1 step on the LONGEST chain leg.
// Closed ledger: packed fp32 (half-rate), all-VALU ships (R11), desync
// (R17), misaligned float4 x-loads (R16), ship-far-h restructure (R19),
// ship-partials-phase bug (R18).
//
// Structure (R15): 1 seq/wave64, lane = L*32 + j*4 + g. Spare-dot DS
// ship double-buffered across bodies: body(m) issues swz16(am2);
// body(m+1) forms d2 = an2_hold + s2p at its top, stores, ships via
// bperm (full-body slack). s1 via permlane16_swap (on-chain, VALU).
// Gates pre-scaled by -log2e (g~ rows -2log2e); cs = c*N2L2E fold.
// Fills 0,1,2 zero L1; bodies 3,4 no store; steady m = 5..Tsz+4,
// store op[m-5].

constexpr int Bsz = 2048;
constexpr int Tsz = 4096;

typedef int v2i __attribute__((ext_vector_type(2)));

template <int CTRL>
__device__ __forceinline__ float dpp(float v) {
    return __int_as_float(
        __builtin_amdgcn_mov_dpp(__float_as_int(v), CTRL, 0xF, 0xF, true));
}
// quad_perm bcast0..3 = 0x00,0x55,0xAA,0xFF; quad xor3 = 0x1B;
// row_half_mirror (xor7) = 0x141; row_mirror (xor15) = 0x140

// v[lane^16] via V_PERMLANE16_SWAP_B32 (VALU; verified bit-exact in R11).
__device__ __forceinline__ float xchg16(float v, bool hi16) {
    const int vi = __float_as_int(v);
    v2i p = __builtin_amdgcn_permlane16_swap(vi, vi, false, false);
    return __int_as_float(hi16 ? p.x : p.y);
}

__device__ __forceinline__ float swz16(float v) {
    // ds_swizzle bit mode, xor 0x10 within each 32-lane group
    return __int_as_float(
        __builtin_amdgcn_ds_swizzle(__float_as_int(v), (16 << 10) | 0x1f));
}

__device__ __forceinline__ float bperm(int addr, float v) {
    return __int_as_float(__builtin_amdgcn_ds_bpermute(addr, __float_as_int(v)));
}

__global__ void __launch_bounds__(256, 2) lstm2_tr(
    const float* __restrict__ x,      // [B, T]
    const float* __restrict__ Wih0,   // [32, 1]
    const float* __restrict__ Whh0,   // [32, 8]
    const float* __restrict__ bih0,   // [32]
    const float* __restrict__ bhh0,   // [32]
    const float* __restrict__ Wih1,   // [32, 8]
    const float* __restrict__ Whh1,   // [32, 8]
    const float* __restrict__ bih1,   // [32]
    const float* __restrict__ bhh1,   // [32]
    const float* __restrict__ Wlin,   // [1, 8]
    const float* __restrict__ blin,   // [1]
    float* __restrict__ out)          // [B, T]
{
    const int tid  = threadIdx.x;
    const int lane = tid & 63;
    const int g    = lane & 3;
    const int j    = (lane >> 2) & 7;
    const int L    = (lane >> 5) & 1;
    const int seq  = blockIdx.x * 4 + (tid >> 6);

    const int jm = j ^ 4;             // mirror lane's unit
    const int r  = g * 8 + j;         // own gate row
    const int rm = g * 8 + jm;        // mirror lane's gate row

    const bool hi16 = (lane & 16) != 0;

    const float NL2E  = -1.4426950408889634f;
    const float N2L2E = -2.8853900817779268f;
    const bool  isG   = (g == 2);
    const float ws    = isG ? N2L2E : NL2E;
    // c-scale fold: g~ lanes produce tanh(g)*N2L2E directly
    const float sA    = isG ? 2.0f * N2L2E : 1.0f;
    const float oA    = isG ? -N2L2E : 0.0f;

    const float* __restrict__ Whh = L ? Whh1 : Whh0;
    const float* __restrict__ bih = L ? bih1 : bih0;
    const float* __restrict__ bhh = L ? bhh1 : bhh0;

    // near weights (own row) + mirror-row weights, k = j^i for i=0..3
    float wn1[4], wm1[4], wn2[4], wm2[4];
#pragma unroll
    for (int i = 0; i < 4; ++i) {
        const int k = j ^ i;
        wn1[i] = Whh[r * 8 + k] * ws;
        wm1[i] = Whh[rm * 8 + k] * ws;
        wn2[i] = L ? Wlin[k] : Wih1[r * 8 + k] * ws;
        wm2[i] = L ? Wlin[k] : Wih1[rm * 8 + k] * ws;
    }
    const float bias = (bih[r] + bhh[r]) * ws;
    const float wx   = L ? 0.0f : Wih0[r] * ws;
    const float b2   = L ? blin[0] : 0.0f;
    const float mL   = L ? 1.0f : 0.0f;
    const float keep = 1.0f - mL;
    const int  xaddr = (lane ^ 32) * 4;   // bpermute: cross layer halves

    const float* __restrict__ xp = x + (size_t)seq * Tsz;
    float* __restrict__ op       = out + (size_t)seq * Tsz;
    const bool storeLane = (lane == 32);

    float hn0 = 0.0f, hn1 = 0.0f, hn2 = 0.0f, hn3 = 0.0f;
    float cs = 0.0f;          // c' = c * N2L2E (scale-folded cell state)
    float recvP = 0.0f;       // bperm result in flight (1-body slack)
    float an2_hold = 0.0f;    // near spare dot from previous body
    float s2p = 0.0f;         // swz16 result in flight (1-body slack)

    auto body = [&](float xt, bool fill, float* storePtr) {
        // ---- top: consume previous body's in-flight DS results
        const float d2 = an2_hold + s2p;   // = full spare dot of h(m-2)
        if (storePtr && storeLane) *storePtr = d2;   // proj -> op[m-5]
        const float rB = recvP;            // bperm(d2(m-1)) result
        recvP = bperm(xaddr, d2);          // issue; consumed next body
        const float t0 = fmaf(mL, rB, fmaf(wx, xt, bias));

        // -- mirror partials from entering hn (= h(m-1))
        float am2 = wm2[0] * hn0;
        am2 = fmaf(wm2[1], hn1, am2);
        am2 = fmaf(wm2[2], hn2, am2);
        am2 = fmaf(wm2[3], hn3, am2);
        s2p = swz16(am2);                  // issue; consumed next body

        // am1 TREE (z-critical leg): depth 3 instead of 4
        float q0 = wm1[0] * hn0;
        q0 = fmaf(wm1[1], hn1, q0);
        float q1 = wm1[2] * hn2;
        q1 = fmaf(wm1[3], hn3, q1);
        const float am1 = q0 + q1;
        const float s1 = xchg16(am1, hi16);   // ON-CHAIN: VALU permlane swap

        // -- near dots; an1 TREE with t0 init (depth 3 pre-combine)
        float a1 = fmaf(wn1[0], hn0, t0);
        a1 = fmaf(wn1[1], hn1, a1);
        float p1 = wn1[2] * hn2;
        p1 = fmaf(wn1[3], hn3, p1);
        float an2 = fmaf(wn2[0], hn0, b2);
        an2 = fmaf(wn2[1], hn1, an2);
        an2 = fmaf(wn2[2], hn2, an2);
        an2 = fmaf(wn2[3], hn3, an2);
        an2_hold = an2;

        // -- z: near tree-combine first, s1 joins last (longest leg)
        const float z = (a1 + p1) + s1;

        // -- activation (pre-scaled): sig, or tanh*N2L2E for g~ lanes
        float a = fmaf(sA,
                       __builtin_amdgcn_rcpf(1.0f + __builtin_amdgcn_exp2f(z)),
                       oA);
        const float gi = dpp<0x00>(a);
        const float gf = dpp<0x55>(a);
        const float gG = dpp<0xAA>(a);        // = tanh(g)*N2L2E (pre-scaled)
        const float go = dpp<0xFF>(a);
        const float go2 = go + go;            // off-critical
        cs = fmaf(gf, cs, gi * gG);           // c' = c*N2L2E
        const float e  = __builtin_amdgcn_exp2f(cs);
        const float rr = __builtin_amdgcn_rcpf(1.0f + e);
        float h = fmaf(go2, rr, -go);         // = go*(2*rr-1)

        if (fill) { h *= keep; cs *= keep; }  // keep L1 state at zero

        // -- near-h gather for next iter (intra-row DPP only)
        const float m7  = dpp<0x141>(h);     // ^7
        const float m15 = dpp<0x140>(h);     // ^15
        hn0 = h;                             // j
        hn1 = dpp<0x1B>(m7);                 // ^7^3  = ^4  -> j^1
        hn2 = dpp<0x141>(m15);               // ^15^7 = ^8  -> j^2
        hn3 = dpp<0x1B>(m15);                // ^15^3 = ^12 -> j^3
    };

    // ---- prologue: bodies 0,1,2 zero L1 state; 3,4 run free, no store
    body(xp[0], true, nullptr);
    body(xp[1], true, nullptr);
    body(xp[2], true, nullptr);
    body(xp[3], false, nullptr);
    body(xp[4], false, nullptr);

    // ---- steady, unrolled x4: m = 5 .. Tsz+4, store op[m-5]
    float xc[4];
#pragma unroll
    for (int u = 0; u < 4; ++u) xc[u] = xp[5 + u];   // x(5..8), Tsz >> 9
    for (int ck = 0; ck < Tsz / 4; ++ck) {
        const int base = 5 + 4 * ck;
        float xf[4];
#pragma unroll
        for (int u = 0; u < 4; ++u) {
            int idx = base + 4 + u;
            idx = (idx < Tsz) ? idx : (Tsz - 1);
            xf[u] = xp[idx];                 // prefetch next chunk (clamped)
        }
#pragma unroll
        for (int u = 0; u < 4; ++u)
            body(xc[u], false, op + (4 * ck + u));   // op[m-5]
#pragma unroll
        for (int u = 0; u < 4; ++u) xc[u] = xf[u];
    }
}

extern "C" void kernel_launch(void* const* d_in, const int* in_sizes, int n_in,
                              void* d_out, int out_size, void* d_ws, size_t ws_size,
                              hipStream_t stream) {
    const float* x    = (const float*)d_in[0];
    const float* Wih0 = (const float*)d_in[1];
    const float* Whh0 = (const float*)d_in[2];
    const float* bih0 = (const float*)d_in[3];
    const float* bhh0 = (const float*)d_in[4];
    const float* Wih1 = (const float*)d_in[5];
    const float* Whh1 = (const float*)d_in[6];
    const float* bih1 = (const float*)d_in[7];
    const float* bhh1 = (const float*)d_in[8];
    const float* Wlin = (const float*)d_in[9];
    const float* blin = (const float*)d_in[10];
    float* out = (float*)d_out;

    dim3 grid(Bsz / 4);   // 4 waves/block, 1 seq/wave -> 512 blocks, 2048 waves
    dim3 block(256);
    hipLaunchKernelGGL(lstm2_tr, grid, block, 0, stream,
                       x, Wih0, Whh0, bih0, bhh0,
                       Wih1, Whh1, bih1, bhh1, Wlin, blin, out);
}

// Round 14
// 842.129 us; speedup vs baseline: 1.0504x; 1.0504x over previous
//
#include <hip/hip_runtime.h>

// 2-layer LSTM, B=2048, T=4096, IN=1, H=8, OUT=1, fp32.
//
// R21 = R15 (best, 855us) with the near-h gather cut from DEPTH 2 to
// DEPTH 1. Model (R8..R20): wall ~500cy/iter = per-seq dependency chain;
// fat nodes are cross-lane DPPs + transcendentals (~25-50cy dep latency),
// not fmas. R15's gather h->m7/m15->hn1..3 is 2 serial cross-lane hops.
// ROW_ROR:4/8/12 (0x124/0x128/0x12C) rotate within the 16-lane row =
// within the own unit-half, preserve g, and fetch all 3 other near units
// in ONE hop (3 parallel DPPs). Near set becomes {j, j-1, j-2, j-3 mod 4
// within half} instead of {j^1,j^2,j^3}; weights re-indexed to match
// (u[i] = (j&4)|((j+4-i)&3); ROR semantics dst[n]=src[(n-N)&15]).
// Dots still sum exactly the 4 own-half units -> same values, slightly
// different summation order. 5 DPP insts -> 3; chain -1 cross-lane step.
// Closed ledger: packed fp32 (half-rate), all-VALU ships (R11), desync
// (R17), float4 x-loads (R16), ship-far-h (R19), tree-dots (R20).
//
// Structure (R15): 1 seq/wave64, lane = L*32 + j*4 + g. Spare-dot DS
// ship double-buffered across bodies: body(m) issues swz16(am2);
// body(m+1) forms d2 = an2_hold + s2p at its top, stores, ships via
// bperm (full-body slack). s1 via permlane16_swap (on-chain, VALU).
// Gates pre-scaled by -log2e (g~ rows -2log2e); cs = c*N2L2E fold.
// Fills 0,1,2 zero L1; bodies 3,4 no store; steady m = 5..Tsz+4,
// store op[m-5].

constexpr int Bsz = 2048;
constexpr int Tsz = 4096;

typedef int v2i __attribute__((ext_vector_type(2)));

template <int CTRL>
__device__ __forceinline__ float dpp(float v) {
    return __int_as_float(
        __builtin_amdgcn_mov_dpp(__float_as_int(v), CTRL, 0xF, 0xF, true));
}
// quad_perm bcast0..3 = 0x00,0x55,0xAA,0xFF; ROW_ROR:N = 0x120|N
// (dst[n] = src[(n-N)&15] within each 16-lane row)

// v[lane^16] via V_PERMLANE16_SWAP_B32 (VALU; verified bit-exact in R11).
__device__ __forceinline__ float xchg16(float v, bool hi16) {
    const int vi = __float_as_int(v);
    v2i p = __builtin_amdgcn_permlane16_swap(vi, vi, false, false);
    return __int_as_float(hi16 ? p.x : p.y);
}

__device__ __forceinline__ float swz16(float v) {
    // ds_swizzle bit mode, xor 0x10 within each 32-lane group
    return __int_as_float(
        __builtin_amdgcn_ds_swizzle(__float_as_int(v), (16 << 10) | 0x1f));
}

__device__ __forceinline__ float bperm(int addr, float v) {
    return __int_as_float(__builtin_amdgcn_ds_bpermute(addr, __float_as_int(v)));
}

__global__ void __launch_bounds__(256, 2) lstm2_rr(
    const float* __restrict__ x,      // [B, T]
    const float* __restrict__ Wih0,   // [32, 1]
    const float* __restrict__ Whh0,   // [32, 8]
    const float* __restrict__ bih0,   // [32]
    const float* __restrict__ bhh0,   // [32]
    const float* __restrict__ Wih1,   // [32, 8]
    const float* __restrict__ Whh1,   // [32, 8]
    const float* __restrict__ bih1,   // [32]
    const float* __restrict__ bhh1,   // [32]
    const float* __restrict__ Wlin,   // [1, 8]
    const float* __restrict__ blin,   // [1]
    float* __restrict__ out)          // [B, T]
{
    const int tid  = threadIdx.x;
    const int lane = tid & 63;
    const int g    = lane & 3;
    const int j    = (lane >> 2) & 7;
    const int L    = (lane >> 5) & 1;
    const int seq  = blockIdx.x * 4 + (tid >> 6);

    const int jm = j ^ 4;             // mirror lane's unit
    const int r  = g * 8 + j;         // own gate row
    const int rm = g * 8 + jm;        // mirror lane's gate row

    const bool hi16 = (lane & 16) != 0;

    const float NL2E  = -1.4426950408889634f;
    const float N2L2E = -2.8853900817779268f;
    const bool  isG   = (g == 2);
    const float ws    = isG ? N2L2E : NL2E;
    // c-scale fold: g~ lanes produce tanh(g)*N2L2E directly
    const float sA    = isG ? 2.0f * N2L2E : 1.0f;
    const float oA    = isG ? -N2L2E : 0.0f;

    const float* __restrict__ Whh = L ? Whh1 : Whh0;
    const float* __restrict__ bih = L ? bih1 : bih0;
    const float* __restrict__ bhh = L ? bhh1 : bhh0;

    // near-unit enumeration delivered by the 1-hop ROR gather:
    //   hn0 = h                      -> unit j
    //   hn1 = dpp ROW_ROR:4  (0x124) -> unit (j&4)|((j+3)&3)   [n-4]
    //   hn2 = dpp ROW_ROR:8  (0x128) -> unit (j&4)|((j+2)&3)
    //   hn3 = dpp ROW_ROR:12 (0x12C) -> unit (j&4)|((j+1)&3)
    int u[4];
    u[0] = j;
    u[1] = (j & 4) | ((j + 3) & 3);
    u[2] = (j & 4) | ((j + 2) & 3);
    u[3] = (j & 4) | ((j + 1) & 3);

    // near weights (own row) + mirror-row weights over units u[i]
    float wn1[4], wm1[4], wn2[4], wm2[4];
#pragma unroll
    for (int i = 0; i < 4; ++i) {
        const int k = u[i];
        wn1[i] = Whh[r * 8 + k] * ws;
        wm1[i] = Whh[rm * 8 + k] * ws;
        wn2[i] = L ? Wlin[k] : Wih1[r * 8 + k] * ws;
        wm2[i] = L ? Wlin[k] : Wih1[rm * 8 + k] * ws;
    }
    const float bias = (bih[r] + bhh[r]) * ws;
    const float wx   = L ? 0.0f : Wih0[r] * ws;
    const float b2   = L ? blin[0] : 0.0f;
    const float mL   = L ? 1.0f : 0.0f;
    const float keep = 1.0f - mL;
    const int  xaddr = (lane ^ 32) * 4;   // bpermute: cross layer halves

    const float* __restrict__ xp = x + (size_t)seq * Tsz;
    float* __restrict__ op       = out + (size_t)seq * Tsz;
    const bool storeLane = (lane == 32);

    float hn0 = 0.0f, hn1 = 0.0f, hn2 = 0.0f, hn3 = 0.0f;
    float cs = 0.0f;          // c' = c * N2L2E (scale-folded cell state)
    float recvP = 0.0f;       // bperm result in flight (1-body slack)
    float an2_hold = 0.0f;    // near spare dot from previous body
    float s2p = 0.0f;         // swz16 result in flight (1-body slack)

    auto body = [&](float xt, bool fill, float* storePtr) {
        // ---- top: consume previous body's in-flight DS results
        const float d2 = an2_hold + s2p;   // = full spare dot of h(m-2)
        if (storePtr && storeLane) *storePtr = d2;   // proj -> op[m-5]
        const float rB = recvP;            // bperm(d2(m-1)) result
        recvP = bperm(xaddr, d2);          // issue; consumed next body
        const float t0 = fmaf(mL, rB, fmaf(wx, xt, bias));

        // -- mirror partials from entering hn (= h(m-1))
        float am2 = wm2[0] * hn0;
        am2 = fmaf(wm2[1], hn1, am2);
        am2 = fmaf(wm2[2], hn2, am2);
        am2 = fmaf(wm2[3], hn3, am2);
        s2p = swz16(am2);                  // issue; consumed next body

        float am1 = wm1[0] * hn0;
        am1 = fmaf(wm1[1], hn1, am1);
        am1 = fmaf(wm1[2], hn2, am1);
        am1 = fmaf(wm1[3], hn3, am1);
        const float s1 = xchg16(am1, hi16);   // ON-CHAIN: VALU permlane swap

        // -- near dots
        float an1 = fmaf(wn1[0], hn0, t0);
        an1 = fmaf(wn1[1], hn1, an1);
        an1 = fmaf(wn1[2], hn2, an1);
        an1 = fmaf(wn1[3], hn3, an1);
        float an2 = fmaf(wn2[0], hn0, b2);
        an2 = fmaf(wn2[1], hn1, an2);
        an2 = fmaf(wn2[2], hn2, an2);
        an2 = fmaf(wn2[3], hn3, an2);
        an2_hold = an2;

        // -- z: near (incl. recvB via t0) + far(ship)
        const float z = an1 + s1;

        // -- activation (pre-scaled): sig, or tanh*N2L2E for g~ lanes
        float a = fmaf(sA,
                       __builtin_amdgcn_rcpf(1.0f + __builtin_amdgcn_exp2f(z)),
                       oA);
        const float gi = dpp<0x00>(a);
        const float gf = dpp<0x55>(a);
        const float gG = dpp<0xAA>(a);        // = tanh(g)*N2L2E (pre-scaled)
        const float go = dpp<0xFF>(a);
        const float go2 = go + go;            // off-critical
        cs = fmaf(gf, cs, gi * gG);           // c' = c*N2L2E
        const float e  = __builtin_amdgcn_exp2f(cs);
        const float rr = __builtin_amdgcn_rcpf(1.0f + e);
        float h = fmaf(go2, rr, -go);         // = go*(2*rr-1)

        if (fill) { h *= keep; cs *= keep; }  // keep L1 state at zero

        // -- near-h gather for next iter: ONE-hop ROW_ROR (3 parallel DPPs)
        hn0 = h;                              // unit j
        hn1 = dpp<0x124>(h);                  // ROW_ROR:4  -> (j&4)|((j+3)&3)
        hn2 = dpp<0x128>(h);                  // ROW_ROR:8  -> (j&4)|((j+2)&3)
        hn3 = dpp<0x12C>(h);                  // ROW_ROR:12 -> (j&4)|((j+1)&3)
    };

    // ---- prologue: bodies 0,1,2 zero L1 state; 3,4 run free, no store
    body(xp[0], true, nullptr);
    body(xp[1], true, nullptr);
    body(xp[2], true, nullptr);
    body(xp[3], false, nullptr);
    body(xp[4], false, nullptr);

    // ---- steady, unrolled x4: m = 5 .. Tsz+4, store op[m-5]
    float xc[4];
#pragma unroll
    for (int u2 = 0; u2 < 4; ++u2) xc[u2] = xp[5 + u2];   // x(5..8)
    for (int ck = 0; ck < Tsz / 4; ++ck) {
        const int base = 5 + 4 * ck;
        float xf[4];
#pragma unroll
        for (int u2 = 0; u2 < 4; ++u2) {
            int idx = base + 4 + u2;
            idx = (idx < Tsz) ? idx : (Tsz - 1);
            xf[u2] = xp[idx];                // prefetch next chunk (clamped)
        }
#pragma unroll
        for (int u2 = 0; u2 < 4; ++u2)
            body(xc[u2], false, op + (4 * ck + u2));   // op[m-5]
#pragma unroll
        for (int u2 = 0; u2 < 4; ++u2) xc[u2] = xf[u2];
    }
}

extern "C" void kernel_launch(void* const* d_in, const int* in_sizes, int n_in,
                              void* d_out, int out_size, void* d_ws, size_t ws_size,
                              hipStream_t stream) {
    const float* x    = (const float*)d_in[0];
    const float* Wih0 = (const float*)d_in[1];
    const float* Whh0 = (const float*)d_in[2];
    const float* bih0 = (const float*)d_in[3];
    const float* bhh0 = (const float*)d_in[4];
    const float* Wih1 = (const float*)d_in[5];
    const float* Whh1 = (const float*)d_in[6];
    const float* bih1 = (const float*)d_in[7];
    const float* bhh1 = (const float*)d_in[8];
    const float* Wlin = (const float*)d_in[9];
    const float* blin = (const float*)d_in[10];
    float* out = (float*)d_out;

    dim3 grid(Bsz / 4);   // 4 waves/block, 1 seq/wave -> 512 blocks, 2048 waves
    dim3 block(256);
    hipLaunchKernelGGL(lstm2_rr, grid, block, 0, stream,
                       x, Wih0, Whh0, bih0, bhh0,
                       Wih1, Whh1, bih1, bhh1, Wlin, blin, out);
}